// Round 5
// baseline (256.749 us; speedup 1.0000x reference)
//
#include <hip/hip_runtime.h>
#include <math.h>
#include <float.h>

#define NB 4
#define NP 4096      // points (and vertices) per batch
#define NT 8192      // triangles
#define NS 128       // triangle splits
#define TCH (NT/NS)  // 64 triangles per chunk
#define PBLK 4       // point-blocks per (b,s): 4 x (256 thr x 4 pts) = 4096 pts
#define GRID (NB*NS*PBLK)  // 2048 blocks
#define TREC 20      // floats per triangle record (5 x float4)
#define EPSD 1e-12

typedef float f2 __attribute__((ext_vector_type(2)));

__device__ __forceinline__ float sigm(float x) { return 1.0f / (1.0f + expf(-x)); }
__device__ __forceinline__ float clamp01f(float x) {
  return __builtin_amdgcn_fmed3f(x, 0.0f, 1.0f);   // v_med3_f32, NaN-free here
}

// ---------------------------------------------------------------------------
// Kernel 1: per-(batch,triangle) record precompute -> GLOBAL (so the dist
// kernel's wave-uniform reads become s_load + SGPR operands — the R3 win).
// Record: r0=[ax ay az abx] r1=[aby abz acx acy] r2=[acz aa am cc]
//         r3=[raa rcc rbb rden] r4=[den bb k1 -]
// Constants in double; den (Gram det) is EXACTLY 0 for degenerate faces ->
// strict min3(vb,vc,va)>0 inside-test excludes them (edge min is exact there).
// Also initializes part2 (cross-block min buffer) and the completion counter,
// eliminating the separate memset node.
// ---------------------------------------------------------------------------
__global__ __launch_bounds__(256) void prep_kernel(
    const float* __restrict__ verts, const int* __restrict__ faces,
    float* __restrict__ tri, unsigned int* __restrict__ part2)
{
  int idx = blockIdx.x * 256 + threadIdx.x;
  if (idx < NB * NP + 1)
    part2[idx] = (idx < NB * NP) ? 0x7F7F7F7Fu : 0u;   // +3.39e38 fill; counter=0
  if (idx >= NB * NT) return;
  int b = idx >> 13;          // / NT
  int t = idx & (NT - 1);
  int f0 = faces[3 * t + 0], f1 = faces[3 * t + 1], f2i = faces[3 * t + 2];
  const float* vv = verts + (size_t)b * 3 * NP;
  float ax = sigm(vv[f0]),  ay = sigm(vv[NP + f0]),  az = sigm(vv[2 * NP + f0]);
  float bx = sigm(vv[f1]),  by = sigm(vv[NP + f1]),  bz = sigm(vv[2 * NP + f1]);
  float cx = sigm(vv[f2i]), cy = sigm(vv[NP + f2i]), cz = sigm(vv[2 * NP + f2i]);
  float abx = bx - ax, aby = by - ay, abz = bz - az;
  float acx = cx - ax, acy = cy - ay, acz = cz - az;
  double aa = (double)abx * abx + (double)aby * aby + (double)abz * abz;
  double am = (double)abx * acx + (double)aby * acy + (double)abz * acz;
  double cc = (double)acx * acx + (double)acy * acy + (double)acz * acz;
  double den = aa * cc - am * am;   // Gram det; exactly 0 iff degenerate
  double bb  = aa - 2.0 * am + cc;  // |bc|^2
  float raa  = (fabs(aa)  < EPSD) ? 1.0f : (float)(1.0 / aa);
  float rcc  = (fabs(cc)  < EPSD) ? 1.0f : (float)(1.0 / cc);
  float rbb  = (fabs(bb)  < EPSD) ? 1.0f : (float)(1.0 / bb);
  float rden = (fabs(den) < EPSD) ? 0.0f : (float)(1.0 / den);
  float* r = tri + (size_t)idx * TREC;
  r[0]  = ax;  r[1]  = ay;  r[2]  = az;
  r[3]  = abx; r[4]  = aby; r[5]  = abz;
  r[6]  = acx; r[7]  = acy; r[8]  = acz;
  r[9]  = (float)aa; r[10] = (float)am; r[11] = (float)cc;
  r[12] = raa; r[13] = rcc; r[14] = rbb; r[15] = rden;
  r[16] = (float)den; r[17] = (float)bb; r[18] = (float)(aa - am); r[19] = 0.0f;
}

// Point-vs-triangle squared distance, 2 points per call (f2), triangle
// constants wave-uniform (SGPRs). dist = inside ? plane-projection
// : min over 3 clamped edge segments. Strict >0 handles degenerates.
__device__ __forceinline__ void tri_point(
    float4 r0, float4 r1, float4 r2, float4 r3, float4 r4,
    f2 px, f2 py, f2 pz, f2& mind)
{
  float abx = r0.w, aby = r1.x, abz = r1.y;
  float acx = r1.z, acy = r1.w, acz = r2.x;
  float aa = r2.y, am = r2.z, cc = r2.w;
  float raa = r3.x, rcc = r3.y, rbb = r3.z, rden = r3.w;
  float den = r4.x, bb = r4.y, k1 = r4.z;

  f2 apx = px - r0.x, apy = py - r0.y, apz = pz - r0.z;
  f2 d1   = apx * abx + apy * aby + apz * abz;
  f2 d2   = apx * acx + apy * acy + apz * acz;
  f2 apap = apx * apx + apy * apy + apz * apz;

  f2 vb = d1 * cc - d2 * am;
  f2 vc = d2 * aa - d1 * am;
  f2 va = den - vb - vc;
  f2 di = apap - (vb * d1 + vc * d2) * rden;

  f2 t2 = d1 + d1;
  f2 tab; tab.x = clamp01f(d1.x * raa); tab.y = clamp01f(d1.y * raa);
  f2 dAB = apap + tab * (tab * aa - t2);

  f2 t4 = d2 + d2;
  f2 tac; tac.x = clamp01f(d2.x * rcc); tac.y = clamp01f(d2.y * rcc);
  f2 dAC = apap + tac * (tac * cc - t4);

  f2 e = d2 - d1 + k1;
  f2 tbc; tbc.x = clamp01f(e.x * rbb); tbc.y = clamp01f(e.y * rbb);
  f2 distB = apap - t2 + aa;
  f2 e2 = e + e;
  f2 dBC = distB + tbc * (tbc * bb - e2);

  float m3x = fminf(fminf(dAB.x, dAC.x), dBC.x);   // v_min3
  float m3y = fminf(fminf(dAB.y, dAC.y), dBC.y);
  float sx  = fminf(fminf(vb.x, vc.x), va.x);      // v_min3
  float sy  = fminf(fminf(vb.y, vc.y), va.y);
  float dx = (sx > 0.0f) ? di.x : m3x;
  float dy = (sy > 0.0f) ? di.y : m3y;
  mind.x = fminf(mind.x, dx);
  mind.y = fminf(mind.y, dy);
}

// ---------------------------------------------------------------------------
// Kernel 2: hot loop + fused finalize. One thread = 4 points (two f2 chains)
// vs one 64-triangle chunk; records read wave-uniformly from global (s_load).
// Cross-block per-point min via uint atomicMin (dists >= 0 -> monotone bits);
// last block (counter trick) computes the masked means and the final scalar.
// ---------------------------------------------------------------------------
__global__ __launch_bounds__(256) void dist_kernel(
    const float* __restrict__ tri, const float* __restrict__ pc,
    unsigned int* __restrict__ part2, unsigned int* __restrict__ counter,
    float* __restrict__ out)
{
  __shared__ unsigned int is_last;
  __shared__ float red[8];

  int bid  = blockIdx.x;
  int pblk = bid & (PBLK - 1);
  int s    = (bid >> 2) & (NS - 1);
  int b    = bid >> 9;
  int tid  = threadIdx.x;

  int p0 = pblk * 1024 + tid;   // points p0, +256, +512, +768
  const float* pp = pc + ((size_t)b * NP + p0) * 3;
  f2 pxA, pyA, pzA, pxB, pyB, pzB;
  pxA.x = pp[0];    pyA.x = pp[1];    pzA.x = pp[2];
  pxA.y = pp[768];  pyA.y = pp[769];  pzA.y = pp[770];
  pxB.x = pp[1536]; pyB.x = pp[1537]; pzB.x = pp[1538];
  pxB.y = pp[2304]; pyB.y = pp[2305]; pzB.y = pp[2306];
  f2 mindA, mindB;
  mindA.x = mindA.y = mindB.x = mindB.y = 3.0e38f;

  const float4* __restrict__ R =
      (const float4*)(tri + (size_t)(b * NT + s * TCH) * TREC);

  #pragma unroll 2
  for (int t = 0; t < TCH; ++t) {
    float4 r0 = R[0], r1 = R[1], r2 = R[2], r3 = R[3], r4 = R[4];
    R += 5;
    tri_point(r0, r1, r2, r3, r4, pxA, pyA, pzA, mindA);
    tri_point(r0, r1, r2, r3, r4, pxB, pyB, pzB, mindB);
  }

  unsigned int* dst = part2 + b * NP + p0;
  atomicMin(dst,       __float_as_uint(fmaxf(mindA.x, 0.0f)));
  atomicMin(dst + 256, __float_as_uint(fmaxf(mindA.y, 0.0f)));
  atomicMin(dst + 512, __float_as_uint(fmaxf(mindB.x, 0.0f)));
  atomicMin(dst + 768, __float_as_uint(fmaxf(mindB.y, 0.0f)));

  __threadfence();   // release our mins before signaling
  if (tid == 0) {
    unsigned int old = atomicAdd(counter, 1u);
    is_last = (old == (unsigned)GRID - 1u) ? 1u : 0u;
  }
  __syncthreads();
  if (is_last) {
    __threadfence();   // acquire all blocks' mins
    float loss = 0.0f;
    for (int bb = 0; bb < NB; ++bb) {
      float sdm = 0.0f, sm = 0.0f;
      for (int p = tid; p < NP; p += 256) {
        unsigned int u = __hip_atomic_load(&part2[bb * NP + p],
                                           __ATOMIC_RELAXED, __HIP_MEMORY_SCOPE_AGENT);
        float m = __uint_as_float(u);
        const float* q = pc + ((size_t)bb * NP + p) * 3;
        bool nz = (q[0] != 0.0f) | (q[1] != 0.0f) | (q[2] != 0.0f);
        if (nz) { sdm += m; sm += 1.0f; }
      }
      for (int off = 32; off > 0; off >>= 1) {
        sdm += __shfl_down(sdm, off, 64);
        sm  += __shfl_down(sm,  off, 64);
      }
      int wv = tid >> 6, ln = tid & 63;
      if (ln == 0) { red[wv] = sdm; red[4 + wv] = sm; }
      __syncthreads();
      if (tid == 0)
        loss += (red[0] + red[1] + red[2] + red[3]) /
                fmaxf(red[4] + red[5] + red[6] + red[7], 1.0f);
      __syncthreads();
    }
    if (tid == 0) out[0] = 0.25f * loss;
  }
}

extern "C" void kernel_launch(void* const* d_in, const int* in_sizes, int n_in,
                              void* d_out, int out_size, void* d_ws, size_t ws_size,
                              hipStream_t stream) {
  const float* verts = (const float*)d_in[0];   // (4,3,16,16,16) f32
  const float* pc    = (const float*)d_in[1];   // (4,4096,3) f32
  const int*   faces = (const int*)d_in[2];     // (8192,3) i32
  float* out = (float*)d_out;

  float* tri            = (float*)d_ws;               // NB*NT*TREC floats (2.6 MB)
  unsigned int* part2   = (unsigned int*)(tri + (size_t)NB * NT * TREC); // NB*NP
  unsigned int* counter = part2 + NB * NP;            // 1 uint

  prep_kernel<<<(NB * NT) / 256, 256, 0, stream>>>(verts, faces, tri, part2);
  dist_kernel<<<GRID, 256, 0, stream>>>(tri, pc, part2, counter, out);
}

// Round 6
// 182.169 us; speedup vs baseline: 1.4094x; 1.4094x over previous
//
#include <hip/hip_runtime.h>
#include <math.h>
#include <float.h>

#define NB 4
#define NP 4096      // points (and vertices) per batch
#define NT 8192      // triangles
#define NS 64        // triangle splits
#define TCH (NT/NS)  // 128 triangles per chunk
#define PBLK 4       // point-blocks per (b,s): 4 x (256 thr x 4 pts) = 4096 pts
#define GRID (NB*NS*PBLK)  // 1024 blocks
#define TREC 20      // floats per triangle record (5 x float4)
#define EPSD 1e-12

typedef float f2 __attribute__((ext_vector_type(2)));

__device__ __forceinline__ float sigm(float x) { return 1.0f / (1.0f + expf(-x)); }
__device__ __forceinline__ float clamp01f(float x) {
  return __builtin_amdgcn_fmed3f(x, 0.0f, 1.0f);   // v_med3_f32; inputs never NaN
}

// ---------------------------------------------------------------------------
// Kernel 1: per-(batch,triangle) record precompute -> GLOBAL, so the dist
// kernel's wave-uniform reads become s_load + SGPR operands (the R3 win; R4
// showed LDS staging loses scalarization and eats bank conflicts).
// Record: r0=[ax ay az abx] r1=[aby abz acx acy] r2=[acz aa am cc]
//         r3=[raa rcc rbb rden] r4=[den bb k1 -]
// Constants in double; den (Gram det) is EXACTLY 0 for degenerate faces ->
// strict min3(vb,vc,va)>0 inside-test excludes them (edge min is exact there).
// Thread 0 also zeroes out[0] for the reduce kernel's atomicAdd.
// ---------------------------------------------------------------------------
__global__ __launch_bounds__(256) void prep_kernel(
    const float* __restrict__ verts, const int* __restrict__ faces,
    float* __restrict__ tri, float* __restrict__ out)
{
  int idx = blockIdx.x * 256 + threadIdx.x;
  if (idx == 0) out[0] = 0.0f;
  if (idx >= NB * NT) return;
  int b = idx >> 13;          // / NT
  int t = idx & (NT - 1);
  int f0 = faces[3 * t + 0], f1 = faces[3 * t + 1], f2i = faces[3 * t + 2];
  const float* vv = verts + (size_t)b * 3 * NP;
  float ax = sigm(vv[f0]),  ay = sigm(vv[NP + f0]),  az = sigm(vv[2 * NP + f0]);
  float bx = sigm(vv[f1]),  by = sigm(vv[NP + f1]),  bz = sigm(vv[2 * NP + f1]);
  float cx = sigm(vv[f2i]), cy = sigm(vv[NP + f2i]), cz = sigm(vv[2 * NP + f2i]);
  float abx = bx - ax, aby = by - ay, abz = bz - az;
  float acx = cx - ax, acy = cy - ay, acz = cz - az;
  double aa = (double)abx * abx + (double)aby * aby + (double)abz * abz;
  double am = (double)abx * acx + (double)aby * acy + (double)abz * acz;
  double cc = (double)acx * acx + (double)acy * acy + (double)acz * acz;
  double den = aa * cc - am * am;   // Gram det; exactly 0 iff degenerate
  double bb  = aa - 2.0 * am + cc;  // |bc|^2
  float raa  = (fabs(aa)  < EPSD) ? 1.0f : (float)(1.0 / aa);
  float rcc  = (fabs(cc)  < EPSD) ? 1.0f : (float)(1.0 / cc);
  float rbb  = (fabs(bb)  < EPSD) ? 1.0f : (float)(1.0 / bb);
  float rden = (fabs(den) < EPSD) ? 0.0f : (float)(1.0 / den);
  float* r = tri + (size_t)idx * TREC;
  r[0]  = ax;  r[1]  = ay;  r[2]  = az;
  r[3]  = abx; r[4]  = aby; r[5]  = abz;
  r[6]  = acx; r[7]  = acy; r[8]  = acz;
  r[9]  = (float)aa; r[10] = (float)am; r[11] = (float)cc;
  r[12] = raa; r[13] = rcc; r[14] = rbb; r[15] = rden;
  r[16] = (float)den; r[17] = (float)bb; r[18] = (float)(aa - am); r[19] = 0.0f;
}

// Point-vs-triangle squared distance, 2 points per call (f2), triangle
// constants wave-uniform (SGPRs). dist = inside ? plane-projection
// : min over 3 clamped edge segments. Strict >0 handles degenerates.
__device__ __forceinline__ void tri_point(
    float4 r0, float4 r1, float4 r2, float4 r3, float4 r4,
    f2 px, f2 py, f2 pz, f2& mind)
{
  float abx = r0.w, aby = r1.x, abz = r1.y;
  float acx = r1.z, acy = r1.w, acz = r2.x;
  float aa = r2.y, am = r2.z, cc = r2.w;
  float raa = r3.x, rcc = r3.y, rbb = r3.z, rden = r3.w;
  float den = r4.x, bb = r4.y, k1 = r4.z;

  f2 apx = px - r0.x, apy = py - r0.y, apz = pz - r0.z;
  f2 d1   = apx * abx + apy * aby + apz * abz;
  f2 d2   = apx * acx + apy * acy + apz * acz;
  f2 apap = apx * apx + apy * apy + apz * apz;

  f2 vb = d1 * cc - d2 * am;
  f2 vc = d2 * aa - d1 * am;
  f2 va = den - vb - vc;
  f2 di = apap - (vb * d1 + vc * d2) * rden;

  f2 t2 = d1 + d1;
  f2 tab; tab.x = clamp01f(d1.x * raa); tab.y = clamp01f(d1.y * raa);
  f2 dAB = apap + tab * (tab * aa - t2);

  f2 t4 = d2 + d2;
  f2 tac; tac.x = clamp01f(d2.x * rcc); tac.y = clamp01f(d2.y * rcc);
  f2 dAC = apap + tac * (tac * cc - t4);

  f2 e = d2 - d1 + k1;
  f2 tbc; tbc.x = clamp01f(e.x * rbb); tbc.y = clamp01f(e.y * rbb);
  f2 distB = apap - t2 + aa;
  f2 e2 = e + e;
  f2 dBC = distB + tbc * (tbc * bb - e2);

  float m3x = fminf(fminf(dAB.x, dAC.x), dBC.x);   // v_min3
  float m3y = fminf(fminf(dAB.y, dAC.y), dBC.y);
  float sx  = fminf(fminf(vb.x, vc.x), va.x);      // v_min3
  float sy  = fminf(fminf(vb.y, vc.y), va.y);
  float dx = (sx > 0.0f) ? di.x : m3x;
  float dy = (sy > 0.0f) ? di.y : m3y;
  mind.x = fminf(mind.x, dx);
  mind.y = fminf(mind.y, dy);
}

// ---------------------------------------------------------------------------
// Kernel 2: hot loop. One thread = 4 points (two independent f2 chains) vs
// one 128-triangle chunk; records read wave-uniformly from global (s_load).
// Plain coalesced stores of the per-split partial mins — no atomics, no
// fences (R4/R5 lesson: fused atomic reduces cost more than a launch).
// ---------------------------------------------------------------------------
__global__ __launch_bounds__(256) void dist_kernel(
    const float* __restrict__ tri, const float* __restrict__ pc,
    float* __restrict__ part)
{
  int bid  = blockIdx.x;
  int pblk = bid & (PBLK - 1);
  int s    = (bid >> 2) & (NS - 1);
  int b    = bid >> 8;
  int tid  = threadIdx.x;

  int p0 = pblk * 1024 + tid;   // points p0, +256, +512, +768
  const float* pp = pc + ((size_t)b * NP + p0) * 3;
  f2 pxA, pyA, pzA, pxB, pyB, pzB;
  pxA.x = pp[0];    pyA.x = pp[1];    pzA.x = pp[2];
  pxA.y = pp[768];  pyA.y = pp[769];  pzA.y = pp[770];
  pxB.x = pp[1536]; pyB.x = pp[1537]; pzB.x = pp[1538];
  pxB.y = pp[2304]; pyB.y = pp[2305]; pzB.y = pp[2306];
  f2 mindA, mindB;
  mindA.x = mindA.y = mindB.x = mindB.y = 3.0e38f;

  const float4* __restrict__ R =
      (const float4*)(tri + (size_t)(b * NT + s * TCH) * TREC);

  #pragma unroll 2
  for (int t = 0; t < TCH; ++t) {
    float4 r0 = R[0], r1 = R[1], r2 = R[2], r3 = R[3], r4 = R[4];
    R += 5;
    tri_point(r0, r1, r2, r3, r4, pxA, pyA, pzA, mindA);
    tri_point(r0, r1, r2, r3, r4, pxB, pyB, pzB, mindB);
  }

  float* dst = part + ((size_t)b * NS + s) * NP + p0;
  dst[0]   = fmaxf(mindA.x, 0.0f);
  dst[256] = fmaxf(mindA.y, 0.0f);
  dst[512] = fmaxf(mindB.x, 0.0f);
  dst[768] = fmaxf(mindB.y, 0.0f);
}

// ---------------------------------------------------------------------------
// Kernel 3: one block per batch (4 x 1024 threads). Each thread owns 4
// points: min over NS split-partials, mask from pc, block-reduce the masked
// sums, then a single contention-free atomicAdd of 0.25*loss_b into out
// (out zeroed by prep). Folds the old final_kernel away -> 3 graph nodes.
// ---------------------------------------------------------------------------
__global__ __launch_bounds__(1024) void reduce_kernel(
    const float* __restrict__ part, const float* __restrict__ pc,
    float* __restrict__ out)
{
  int b = blockIdx.x, tid = threadIdx.x;
  float sdm = 0.0f, sm = 0.0f;
  #pragma unroll
  for (int k = 0; k < 4; ++k) {
    int p = k * 1024 + tid;
    float m = 3.0e38f;
    #pragma unroll
    for (int s = 0; s < NS; ++s)
      m = fminf(m, part[((size_t)b * NS + s) * NP + p]);
    const float* q = pc + ((size_t)b * NP + p) * 3;
    bool nz = (q[0] != 0.0f) | (q[1] != 0.0f) | (q[2] != 0.0f);
    if (nz) { sdm += m; sm += 1.0f; }
  }
  for (int off = 32; off > 0; off >>= 1) {
    sdm += __shfl_down(sdm, off, 64);
    sm  += __shfl_down(sm,  off, 64);
  }
  __shared__ float s1[16], s2[16];
  int wv = tid >> 6, ln = tid & 63;
  if (ln == 0) { s1[wv] = sdm; s2[wv] = sm; }
  __syncthreads();
  if (wv == 0) {
    sdm = (ln < 16) ? s1[ln] : 0.0f;
    sm  = (ln < 16) ? s2[ln] : 0.0f;
    for (int off = 8; off > 0; off >>= 1) {
      sdm += __shfl_down(sdm, off, 64);
      sm  += __shfl_down(sm,  off, 64);
    }
    if (ln == 0) atomicAdd(out, 0.25f * (sdm / fmaxf(sm, 1.0f)));
  }
}

extern "C" void kernel_launch(void* const* d_in, const int* in_sizes, int n_in,
                              void* d_out, int out_size, void* d_ws, size_t ws_size,
                              hipStream_t stream) {
  const float* verts = (const float*)d_in[0];   // (4,3,16,16,16) f32
  const float* pc    = (const float*)d_in[1];   // (4,4096,3) f32
  const int*   faces = (const int*)d_in[2];     // (8192,3) i32
  float* out = (float*)d_out;

  float* tri  = (float*)d_ws;                     // NB*NT*TREC floats (2.6 MB)
  float* part = tri + (size_t)NB * NT * TREC;     // NB*NS*NP floats (4 MB)

  prep_kernel<<<(NB * NT) / 256, 256, 0, stream>>>(verts, faces, tri, out);
  dist_kernel<<<GRID, 256, 0, stream>>>(tri, pc, part);
  reduce_kernel<<<NB, 1024, 0, stream>>>(part, pc, out);
}